// Round 1
// baseline (24.021 us; speedup 1.0000x reference)
//
#include <hip/hip_runtime.h>

// Problem constants (from reference): B=32, M=12, T=512, G=256
#define B_ 32
#define M_ 12
#define T_ 512
#define G_ 256

// out[b][g][2m+0] = dens[b,m,g]   = sum_t mask[b,m,t] * exp(-0.5*(grid g - x[b,t])^2/sigma0^2)
// out[b][g][2m+1] = conv/(dens+1e-8), conv = sum_t y[b,m,t] * exp(-0.5*(..)^2/sigma1^2)

template<int TC>
__global__ __launch_bounds__(256) void k_partial(
    const float* __restrict__ y, const float* __restrict__ x,
    const int* __restrict__ mask, const float* __restrict__ grid,
    const float* __restrict__ sigma, float* __restrict__ part)
{
    constexpr int TCH = T_ / TC;   // t-chunk length
    const int b  = blockIdx.x;
    const int tc = blockIdx.y;
    const int g  = threadIdx.x;    // G_ == 256 == blockDim.x
    const int t0 = tc * TCH;

    __shared__ __align__(16) float xs[TCH];
    __shared__ __align__(16) float ys[TCH][M_];
    __shared__ __align__(16) float ms[TCH][M_];

    // stage x slice
    for (int i = g; i < TCH; i += 256) xs[i] = x[b * T_ + t0 + i];
    // stage y and mask slices; global reads coalesced over t, LDS layout [t][m]
    for (int i = g; i < TCH * M_; i += 256) {
        const int m  = i / TCH;
        const int tt = i % TCH;
        ys[tt][m] = y[(b * M_ + m) * T_ + t0 + tt];
        ms[tt][m] = (float)mask[(b * M_ + m) * T_ + t0 + tt];
    }
    __syncthreads();

    const float gv = grid[g];
    const float s0 = sigma[0], s1 = sigma[1];
    const float LOG2E = 1.4426950408889634f;
    const float c0 = (-0.5f / (s0 * s0)) * LOG2E;   // exponent coeff for exp2
    const float c1 = (-0.5f / (s1 * s1)) * LOG2E;

    float dens[M_], conv[M_];
#pragma unroll
    for (int m = 0; m < M_; ++m) { dens[m] = 0.f; conv[m] = 0.f; }

    for (int tt = 0; tt < TCH; ++tt) {
        const float d  = gv - xs[tt];
        const float d2 = d * d;
        const float w0 = __builtin_amdgcn_exp2f(d2 * c0);
        const float w1 = __builtin_amdgcn_exp2f(d2 * c1);
        const float4* yp = (const float4*)(&ys[tt][0]);
        const float4* mp = (const float4*)(&ms[tt][0]);
#pragma unroll
        for (int q = 0; q < 3; ++q) {
            const float4 yv = yp[q];
            const float4 mv = mp[q];
            dens[q*4+0] += mv.x * w0;  conv[q*4+0] += yv.x * w1;
            dens[q*4+1] += mv.y * w0;  conv[q*4+1] += yv.y * w1;
            dens[q*4+2] += mv.z * w0;  conv[q*4+2] += yv.z * w1;
            dens[q*4+3] += mv.w * w0;  conv[q*4+3] += yv.w * w1;
        }
    }

    // partials layout: part[b][tc][g][m][c], c fastest
    float* pb = part + (size_t)((b * TC + tc) * G_ + g) * (2 * M_);
#pragma unroll
    for (int m = 0; m < M_; ++m) {
        float2 p; p.x = dens[m]; p.y = conv[m];
        *(float2*)&pb[2 * m] = p;
    }
}

template<int TC>
__global__ __launch_bounds__(256) void k_reduce(
    const float* __restrict__ part, float* __restrict__ out)
{
    const int idx = blockIdx.x * 256 + threadIdx.x;  // over B*G*M
    if (idx >= B_ * G_ * M_) return;
    const int m = idx % M_;
    const int g = (idx / M_) % G_;
    const int b = idx / (M_ * G_);

    float dens = 0.f, conv = 0.f;
#pragma unroll
    for (int tc = 0; tc < TC; ++tc) {
        const float2 p = *(const float2*)&part[
            (size_t)((b * TC + tc) * G_ + g) * (2 * M_) + 2 * m];
        dens += p.x; conv += p.y;
    }
    float2 o; o.x = dens; o.y = conv / (dens + 1e-8f);
    *(float2*)&out[(size_t)(b * G_ + g) * (2 * M_) + 2 * m] = o;
}

extern "C" void kernel_launch(void* const* d_in, const int* in_sizes, int n_in,
                              void* d_out, int out_size, void* d_ws, size_t ws_size,
                              hipStream_t stream) {
    const float* y     = (const float*)d_in[0];
    const float* x     = (const float*)d_in[1];
    const int*   mask  = (const int*)d_in[2];
    const float* grid  = (const float*)d_in[3];
    const float* sigma = (const float*)d_in[4];
    float* out = (float*)d_out;

    const int nred = (B_ * G_ * M_) / 256;  // 384 blocks

    auto need = [](int tc) { return (size_t)B_ * tc * G_ * 2 * M_ * sizeof(float); };

    if (ws_size >= need(16)) {
        float* part = (float*)d_ws;
        k_partial<16><<<dim3(B_, 16), 256, 0, stream>>>(y, x, mask, grid, sigma, part);
        k_reduce<16><<<nred, 256, 0, stream>>>(part, out);
    } else if (ws_size >= need(8)) {
        float* part = (float*)d_ws;
        k_partial<8><<<dim3(B_, 8), 256, 0, stream>>>(y, x, mask, grid, sigma, part);
        k_reduce<8><<<nred, 256, 0, stream>>>(part, out);
    } else if (ws_size >= need(4)) {
        float* part = (float*)d_ws;
        k_partial<4><<<dim3(B_, 4), 256, 0, stream>>>(y, x, mask, grid, sigma, part);
        k_reduce<4><<<nred, 256, 0, stream>>>(part, out);
    } else {
        // TC=1: partial layout == output layout, write in place then finalize
        k_partial<1><<<dim3(B_, 1), 256, 0, stream>>>(y, x, mask, grid, sigma, out);
        k_reduce<1><<<nred, 256, 0, stream>>>(out, out);
    }
}

// Round 2
// 20.107 us; speedup vs baseline: 1.1946x; 1.1946x over previous
//
#include <hip/hip_runtime.h>

// Problem constants: B=32, M=12, T=512, G=256
#define B_ 32
#define M_ 12
#define T_ 512
#define G_ 256

#define GS 16             // g-values per block
#define NCHUNK (G_ / GS)  // 16 chunks -> grid (32,16) = 512 blocks

// LDS layout (floats):
//   ys [0, 6144)      y staged as [t][12] with slot rotation
//   ms [6144, 12288)  mask (as float) same layout
//   xs [12288, 12800) x[b][t]
// After main loop (re-sync), whole buffer reused as reduce scratch:
//   red[tid][0..47], row stride 52 floats (pad vs 16-bank stride)
#define YS_OFF 0
#define MS_OFF 6144
#define XS_OFF 12288
#define RED_STRIDE 52
#define LDS_FLOATS 13312   // max(12800, 256*52)

// out[b][g][2m+0] = dens = sum_t mask[b,m,t] * exp(-0.5*(grid[g]-x[b,t])^2/s0^2)
// out[b][g][2m+1] = conv/(dens+1e-8), conv = sum_t y[b,m,t]*exp(-0.5*(..)^2/s1^2)

__global__ __launch_bounds__(256, 2) void k_fused(
    const float* __restrict__ y, const float* __restrict__ x,
    const int* __restrict__ mask, const float* __restrict__ grid,
    const float* __restrict__ sigma, float* __restrict__ out)
{
    __shared__ float lds[LDS_FLOATS];
    const int b     = blockIdx.x;
    const int gbase = blockIdx.y * GS;
    const int tid   = threadIdx.x;
    const int gq    = tid >> 5;   // 0..7  (owns g = gbase+gq and gbase+gq+8)
    const int ts    = tid & 31;   // 0..31 (t-slice: t = ts + 32k)

    // ---- stage x ----
    for (int i = tid; i < T_; i += 256)
        lds[XS_OFF + i] = x[b * T_ + i];

    // ---- stage y, mask: row t holds m=0..11; logical slot q=m>>2 placed at
    //      physical slot (q + (t>>3)%3) % 3 to de-conflict main-loop b128 reads.
    //      Store addresses are a within-row permutation of linear i -> conflict-free.
    for (int i = tid; i < T_ * M_; i += 256) {
        const int t = i / 12;
        const int m = i - t * 12;
        const int q = m >> 2, p = m & 3;
        int qq = q + ((t >> 3) % 3);
        if (qq >= 3) qq -= 3;
        const int off = t * 12 + (qq << 2) + p;
        lds[YS_OFF + off] = y[(b * M_ + m) * T_ + t];
        lds[MS_OFF + off] = (float)mask[(b * M_ + m) * T_ + t];
    }
    __syncthreads();

    const float gv0 = grid[gbase + gq];
    const float gv1 = grid[gbase + gq + 8];
    const float s0 = sigma[0], s1 = sigma[1];
    const float LOG2E = 1.4426950408889634f;
    const float c0 = (-0.5f / (s0 * s0)) * LOG2E;
    const float c1 = (-0.5f / (s1 * s1)) * LOG2E;

    // acc[h][m] = {dens, conv} for g = gbase+gq+8h
    float2 acc[2][12];
#pragma unroll
    for (int h = 0; h < 2; ++h)
#pragma unroll
        for (int m = 0; m < M_; ++m) acc[h][m] = make_float2(0.f, 0.f);

    for (int k = 0; k < T_ / 32; ++k) {
        const int t = ts + 32 * k;
        const float xv = lds[XS_OFF + t];
        const float d0 = gv0 - xv, d1 = gv1 - xv;
        const float p0 = d0 * d0, p1 = d1 * d1;
        const float e00 = __builtin_amdgcn_exp2f(p0 * c0);  // g0, sigma0 (dens)
        const float e01 = __builtin_amdgcn_exp2f(p0 * c1);  // g0, sigma1 (conv)
        const float e10 = __builtin_amdgcn_exp2f(p1 * c0);
        const float e11 = __builtin_amdgcn_exp2f(p1 * c1);
        const int rowt = t * 12;
        int r = (t >> 3) % 3;
#pragma unroll
        for (int q = 0; q < 3; ++q) {
            int qq = q + r; if (qq >= 3) qq -= 3;
            const int off = rowt + (qq << 2);
            const float4 yv = *(const float4*)&lds[YS_OFF + off];
            const float4 mv = *(const float4*)&lds[MS_OFF + off];
            const float* yf = (const float*)&yv;
            const float* mf = (const float*)&mv;
#pragma unroll
            for (int j = 0; j < 4; ++j) {
                const int m = q * 4 + j;
                acc[0][m].x += mf[j] * e00;
                acc[0][m].y += yf[j] * e01;
                acc[1][m].x += mf[j] * e10;
                acc[1][m].y += yf[j] * e11;
            }
        }
    }

    // ---- reduce over the 32 t-slices per g ----
    __syncthreads();  // everyone done READING ys/ms before overwrite
    {
        const float4* av = (const float4*)&acc[0][0];
#pragma unroll
        for (int j = 0; j < 12; ++j)
            *(float4*)&lds[tid * RED_STRIDE + 4 * j] = av[j];
    }
    __syncthreads();

    if (tid < GS * M_) {            // 192 finalize threads: one (g,m) each
        const int og = tid / 12;    // 0..15
        const int m  = tid - og * 12;
        const int h  = og >> 3;     // which g-half
        const int q8 = og & 7;      // gq of owner threads
        float dens = 0.f, conv = 0.f;
#pragma unroll
        for (int t5 = 0; t5 < 32; ++t5) {
            const float2 v = *(const float2*)&lds[(q8 * 32 + t5) * RED_STRIDE + 2 * (h * 12 + m)];
            dens += v.x;
            conv += v.y;
        }
        float2 o;
        o.x = dens;
        o.y = conv / (dens + 1e-8f);
        *(float2*)&out[(size_t)((b * G_ + gbase + og) * 2 * M_) + 2 * m] = o;
    }
}

extern "C" void kernel_launch(void* const* d_in, const int* in_sizes, int n_in,
                              void* d_out, int out_size, void* d_ws, size_t ws_size,
                              hipStream_t stream) {
    const float* y     = (const float*)d_in[0];
    const float* x     = (const float*)d_in[1];
    const int*   mask  = (const int*)d_in[2];
    const float* grid  = (const float*)d_in[3];
    const float* sigma = (const float*)d_in[4];
    float* out = (float*)d_out;

    k_fused<<<dim3(B_, NCHUNK), 256, 0, stream>>>(y, x, mask, grid, sigma, out);
}